// Round 5
// baseline (648.254 us; speedup 1.0000x reference)
//
#include <hip/hip_runtime.h>
#include <hip/hip_bf16.h>

typedef unsigned short u16;
typedef __bf16 bf16x8 __attribute__((ext_vector_type(8)));
typedef float floatx4 __attribute__((ext_vector_type(4)));

__device__ __forceinline__ __bf16 f2b(float f) {
    __hip_bfloat16 h = __float2bfloat16(f);
    return *reinterpret_cast<__bf16*>(&h);
}

// load 8 contiguous elements as bf16x8 (16B/32B-aligned source)
__device__ __forceinline__ bf16x8 ld8(const __hip_bfloat16* p) {
    return *(const bf16x8*)(const void*)p;
}
__device__ __forceinline__ bf16x8 ld8(const float* p) {
    float4 a = ((const float4*)p)[0];
    float4 b = ((const float4*)p)[1];
    bf16x8 r;
    r[0] = f2b(a.x); r[1] = f2b(a.y); r[2] = f2b(a.z); r[3] = f2b(a.w);
    r[4] = f2b(b.x); r[5] = f2b(b.y); r[6] = f2b(b.z); r[7] = f2b(b.w);
    return r;
}

__device__ __forceinline__ void storev(float* p, float v) { *p = v; }
__device__ __forceinline__ void storev(__hip_bfloat16* p, float v) { *p = __float2bfloat16(v); }

// ============================================================================
// NT GEMM: C[m,n] = scale * sum_k A[m,k] * B[n,k]
// A: [M,K] row-major (fp32 or bf16), B: [N,K] row-major (fp32 or bf16),
// C: [M,N] (fp32 or bf16). fp32 inputs are converted to bf16 in registers
// during staging (RNE); MFMA runs bf16 with fp32 accumulation.
// 128x128 tile, BK=32, 256 threads = 4 waves, each wave 64x64 via 4x4 MFMAs.
// M,N % 128 == 0, K % 32 == 0 (true for all shapes here).
// ============================================================================
template <typename TA, typename TB, typename OutT>
__global__ __launch_bounds__(256)
void gemm_nt(const TA* __restrict__ A, const TB* __restrict__ B,
             OutT* __restrict__ C, int M, int N, int K,
             long sA, long sB, long sC, float scale)
{
    A += (long)blockIdx.z * sA;
    B += (long)blockIdx.z * sB;
    C += (long)blockIdx.z * sC;

    __shared__ __align__(16) u16 As[128 * 32];
    __shared__ __align__(16) u16 Bs[128 * 32];

    const int tid  = threadIdx.x;
    const int wave = tid >> 6;
    const int lane = tid & 63;

    const int m_blk = blockIdx.y * 128;
    const int n_blk = blockIdx.x * 128;

    // staging map: vec-slot e (0..511) -> tile row e>>2, k-col (e&3)*8 (8 elems)
    const int row0 = tid >> 2;            // pass 0: e = tid
    const int row1 = (256 + tid) >> 2;    // pass 1: e = 256 + tid
    const int kc   = (tid & 3) * 8;

    floatx4 acc[4][4];
#pragma unroll
    for (int i = 0; i < 4; i++)
#pragma unroll
        for (int j = 0; j < 4; j++) acc[i][j] = (floatx4){0.f, 0.f, 0.f, 0.f};

    const int wm = (wave >> 1) * 64;  // wave sub-tile origin
    const int wn = (wave & 1) * 64;
    const int fr = lane & 15;         // fragment m (A) / n (B) index
    const int fk = (lane >> 4) * 8;   // fragment k offset

    for (int k0 = 0; k0 < K; k0 += 32) {
        // 1. global -> VGPR (convert to bf16 if needed)
        bf16x8 va0 = ld8(A + (long)(m_blk + row0) * K + k0 + kc);
        bf16x8 va1 = ld8(A + (long)(m_blk + row1) * K + k0 + kc);
        bf16x8 vb0 = ld8(B + (long)(n_blk + row0) * K + k0 + kc);
        bf16x8 vb1 = ld8(B + (long)(n_blk + row1) * K + k0 + kc);

        // 2. protect LDS from previous iteration's readers
        __syncthreads();

        // 3. VGPR -> LDS
        *(bf16x8*)&As[(size_t)tid * 8]         = va0;
        *(bf16x8*)&As[(size_t)(256 + tid) * 8] = va1;
        *(bf16x8*)&Bs[(size_t)tid * 8]         = vb0;
        *(bf16x8*)&Bs[(size_t)(256 + tid) * 8] = vb1;

        __syncthreads();

        // 4. LDS -> fragments, MFMA
        bf16x8 af[4], bfv[4];
#pragma unroll
        for (int i = 0; i < 4; i++)
            af[i] = *(const bf16x8*)&As[(wm + i * 16 + fr) * 32 + fk];
#pragma unroll
        for (int j = 0; j < 4; j++)
            bfv[j] = *(const bf16x8*)&Bs[(wn + j * 16 + fr) * 32 + fk];

#pragma unroll
        for (int i = 0; i < 4; i++)
#pragma unroll
            for (int j = 0; j < 4; j++)
                acc[i][j] = __builtin_amdgcn_mfma_f32_16x16x32_bf16(
                    af[i], bfv[j], acc[i][j], 0, 0, 0);
    }

    // epilogue: C/D layout col=lane&15, row=(lane>>4)*4+reg  [m89/m91]
    const int c_col0 = n_blk + wn + fr;
    const int c_row0 = m_blk + wm + (lane >> 4) * 4;
#pragma unroll
    for (int i = 0; i < 4; i++) {
#pragma unroll
        for (int r = 0; r < 4; r++) {
            const long row = c_row0 + i * 16 + r;
#pragma unroll
            for (int j = 0; j < 4; j++) {
                storev(&C[row * N + c_col0 + j * 16], acc[i][j][r] * scale);
            }
        }
    }
}

// ============================================================================
// In-place fp32 row softmax over 2048 logits. One block per row; each thread
// rewrites exactly the elements it read (same dtype) -> race-free.
// ============================================================================
__global__ __launch_bounds__(256)
void softmax_rows_2048(float* __restrict__ X)
{
    const long row = blockIdx.x;
    const int t = threadIdx.x;
    const int wave = t >> 6, lane = t & 63;

    __shared__ float red[8];

    float v[8];
    float m = -1e30f;
#pragma unroll
    for (int i = 0; i < 8; i++) {
        v[i] = X[row * 2048 + t + i * 256];
        m = fmaxf(m, v[i]);
    }
#pragma unroll
    for (int o = 32; o > 0; o >>= 1) m = fmaxf(m, __shfl_xor(m, o, 64));
    if (lane == 0) red[wave] = m;
    __syncthreads();
    m = fmaxf(fmaxf(red[0], red[1]), fmaxf(red[2], red[3]));

    float s = 0.f;
#pragma unroll
    for (int i = 0; i < 8; i++) { v[i] = __expf(v[i] - m); s += v[i]; }
#pragma unroll
    for (int o = 32; o > 0; o >>= 1) s += __shfl_xor(s, o, 64);
    if (lane == 0) red[4 + wave] = s;
    __syncthreads();
    s = red[4] + red[5] + red[6] + red[7];

    const float inv = 1.f / s;
#pragma unroll
    for (int i = 0; i < 8; i++)
        X[row * 2048 + t + i * 256] = v[i] * inv;
}

// ============================================================================
// Pipeline: Q/K/Vt projections (fp32 in -> bf16 out) -> per batch
// {logits fp32, in-place fp32 softmax, P(fp32)@Vt(bf16) -> AO bf16} ->
// output projection (bf16 x fp32 -> FP32 OUT: reference output dtype is
// float32, so d_out is float* — R4's bf16 write was the bug).
// AO aliases Q (batch b's Q dead after its logit GEMM). Workspace: 64 MiB.
// ============================================================================
extern "C" void kernel_launch(void* const* d_in, const int* in_sizes, int n_in,
                              void* d_out, int out_size, void* d_ws, size_t ws_size,
                              hipStream_t stream)
{
    const float* x   = (const float*)d_in[0];  // [4,2048,1024] fp32
    const float* mem = (const float*)d_in[1];  // [4,2048,1024] fp32
    const float* Wq  = (const float*)d_in[2];  // [1024,1024] fp32 [out,in]
    const float* Wk  = (const float*)d_in[3];
    const float* Wv  = (const float*)d_in[4];
    const float* Wo  = (const float*)d_in[5];
    float* out = (float*)d_out;                // fp32 per reference output dtype

    constexpr int B = 4, L = 2048, D = 1024;
    constexpr size_t CH = 1u << 24;  // 16 MiB chunks
    typedef __hip_bfloat16 bf;

    char*  ws = (char*)d_ws;
    bf*    Q  = (bf*)(ws + 0 * CH);     // [8192,1024] bf16; AO aliases this
    bf*    Kp = (bf*)(ws + 1 * CH);     // [8192,1024] bf16
    bf*    Vt = (bf*)(ws + 2 * CH);     // [4][1024,2048] bf16
    float* Lg = (float*)(ws + 3 * CH);  // [2048,2048] fp32 logits -> P in place
    bf*    AO = Q;                      // alias (see header)

    dim3 blk(256);
    const float qscale = 0.03125f;  // 1024^-0.5

    // Q = x @ Wq^T * scale ; K = mem @ Wk^T
    gemm_nt<float, float, bf><<<dim3(D / 128, (B * L) / 128, 1), blk, 0, stream>>>(
        x, Wq, Q, B * L, D, D, 0, 0, 0, qscale);
    gemm_nt<float, float, bf><<<dim3(D / 128, (B * L) / 128, 1), blk, 0, stream>>>(
        mem, Wk, Kp, B * L, D, D, 0, 0, 0, 1.f);
    // Vt[b][e,m'] = sum_d Wv[e,d] * mem[b][m',d]
    gemm_nt<float, float, bf><<<dim3(L / 128, D / 128, B), blk, 0, stream>>>(
        Wv, mem, Vt, D, L, D, 0, (long)L * D, (long)D * L, 1.f);

    for (int b = 0; b < B; b++) {
        const long off = (long)b * L * D;
        // logits[q,m] = Q[q,:] . K[m,:]  (fp32 out — no bf16 rounding of z)
        gemm_nt<bf, bf, float><<<dim3(L / 128, L / 128, 1), blk, 0, stream>>>(
            Q + off, Kp + off, Lg, L, L, D, 0, 0, 0, 1.f);
        softmax_rows_2048<<<dim3(L), blk, 0, stream>>>(Lg);
        // AO[q,e] = sum_m P[q,m] * Vt[e,m]; P read fp32, rounded at staging.
        // (AO[b] overwrites Q[b] — safe: Q[b] dead after its logit GEMM.)
        gemm_nt<float, bf, bf><<<dim3(D / 128, L / 128, 1), blk, 0, stream>>>(
            Lg, Vt + (long)b * D * L, AO + off, L, D, L, 0, 0, 0, 1.f);
    }

    // out = AO @ Wo^T   (bf16 x fp32 -> fp32)
    gemm_nt<bf, float, float><<<dim3(D / 128, (B * L) / 128, 1), blk, 0, stream>>>(
        AO, Wo, out, B * L, D, D, 0, 0, 0, 1.f);
}